// Round 1
// baseline (8872.998 us; speedup 1.0000x reference)
//
#include <hip/hip_runtime.h>
#include <math.h>

// Problem constants
#define NB 256      // n_trials
#define TT 200      // timesteps
#define IDIM 128
#define NDIM 1024
#define ODIM 128

// Workspace layout (float offsets). Total = 2,359,296 floats = 9,437,184 bytes.
#define JT_OFF   0          // Jt[k][n]  : 1024*1024
#define BT_OFF   1048576    // Bt[i][n]  : 128*1024
#define WT_OFF   1179648    // Wt[n][o]  : 1024*128
#define S_OFF    1310720    // S[2][256][1024] sigmoid(V) double-buffered
#define TH_OFF   1835008    // Th[2][256][1024] tanh(V) double-buffered

// Output layout (float offsets into d_out)
#define VT_STRIDE_B 205824          // 201*1024
#define ZT_BASE   52690944          // 256*201*1024
#define OUTS_BASE 105381888         // 2*256*201*1024

__global__ __launch_bounds__(256) void rsnn_prologue(
    const float* __restrict__ J, const float* __restrict__ Bm,
    const float* __restrict__ W, float* __restrict__ ws,
    float* __restrict__ out) {
  int blk = blockIdx.x, tid = threadIdx.x;
  __shared__ float tile[32][33];
  if (blk < 1024) {
    // transpose J (1024x1024) -> Jt[k][n]
    int tk = blk >> 5, tn = blk & 31;
    int k0 = tk * 32, n0 = tn * 32;
    int c = tid & 31, r0 = tid >> 5;
#pragma unroll
    for (int j = 0; j < 4; ++j) {
      int r = r0 + j * 8;
      tile[r][c] = J[(n0 + r) * NDIM + (k0 + c)];
    }
    __syncthreads();
#pragma unroll
    for (int j = 0; j < 4; ++j) {
      int r = r0 + j * 8;
      ws[JT_OFF + (k0 + r) * NDIM + (n0 + c)] = tile[c][r];
    }
  } else if (blk < 1152) {
    // transpose B (1024x128) -> Bt[i][n]
    int b2 = blk - 1024;
    int tn = b2 >> 2, ti = b2 & 3;
    int n0 = tn * 32, i0 = ti * 32;
    int c = tid & 31, r0 = tid >> 5;
#pragma unroll
    for (int j = 0; j < 4; ++j) {
      int r = r0 + j * 8;
      tile[r][c] = Bm[(n0 + r) * IDIM + (i0 + c)];
    }
    __syncthreads();
#pragma unroll
    for (int j = 0; j < 4; ++j) {
      int r = r0 + j * 8;
      ws[BT_OFF + (i0 + r) * NDIM + (n0 + c)] = tile[c][r];
    }
  } else if (blk < 1280) {
    // transpose W (128x1024) -> Wt[n][o]
    int b3 = blk - 1152;
    int to = b3 >> 5, tn = b3 & 31;
    int o0 = to * 32, n0 = tn * 32;
    int c = tid & 31, r0 = tid >> 5;
#pragma unroll
    for (int j = 0; j < 4; ++j) {
      int r = r0 + j * 8;
      tile[r][c] = W[(o0 + r) * NDIM + (n0 + c)];
    }
    __syncthreads();
#pragma unroll
    for (int j = 0; j < 4; ++j) {
      int r = r0 + j * 8;
      ws[WT_OFF + (n0 + r) * ODIM + (o0 + c)] = tile[c][r];
    }
  } else {
    // init: S parity0 = sigmoid(0) = 0.5 ; vt[:,0,:] = 0 ; zt[:,0,:] = 0
    int i0 = (blk - 1280) * 256 + tid;
    for (int it = i0; it < NB * NDIM; it += 256 * 256) {
      int b = it >> 10, n = it & 1023;
      ws[S_OFF + it] = 0.5f;
      out[b * VT_STRIDE_B + n] = 0.0f;
      out[ZT_BASE + b * VT_STRIDE_B + n] = 0.0f;
    }
  }
}

// One time step. Blocks [0,512): recurrent update (8 batch x 64 neuron tile,
// 4 waves split K=1152). Blocks [512,640): output projection for step s-1
// (4 batch x 64 out tile, 4 waves split K=1024).
__global__ __launch_bounds__(256, 2) void rsnn_step(
    const float* __restrict__ inputs, const float* __restrict__ noise,
    float* __restrict__ ws, float* __restrict__ out, int s) {
  int blk = blockIdx.x, tid = threadIdx.x;
  int l = tid & 63;
  int w = __builtin_amdgcn_readfirstlane(tid >> 6);  // wave id, SGPR-uniform
  __shared__ float red[4][8][64];

  if (blk < 512) {
    if (s >= TT) return;
    int b0 = (blk >> 4) * 8;    // 32 batch tiles
    int n0 = (blk & 15) * 64;   // 16 neuron tiles
    const float* Sb = ws + S_OFF + (s & 1) * (NB * NDIM);
    const float* Jt = ws + JT_OFF;
    float acc[8] = {0.f, 0.f, 0.f, 0.f, 0.f, 0.f, 0.f, 0.f};

    int kb = w * 288;                       // waves cover [0,1152) in quarters
    int kje = (kb + 288 > NDIM) ? NDIM : (kb + 288);
#pragma unroll 4
    for (int k = kb; k < kje; ++k) {
      float jv = Jt[k * NDIM + n0 + l];     // coalesced vector load
#pragma unroll
      for (int i = 0; i < 8; ++i)           // wave-uniform -> scalar loads
        acc[i] = fmaf(Sb[(b0 + i) * NDIM + k], jv, acc[i]);
    }
    if (w == 3) {  // input projection part: k in [1024,1152)
#pragma unroll 4
      for (int k2 = 0; k2 < IDIM; ++k2) {
        float bv = ws[BT_OFF + k2 * NDIM + n0 + l];
#pragma unroll
        for (int i = 0; i < 8; ++i)
          acc[i] = fmaf(inputs[((b0 + i) * TT + s) * IDIM + k2], bv, acc[i]);
      }
    }
#pragma unroll
    for (int i = 0; i < 8; ++i) red[w][i][l] = acc[i];
    __syncthreads();

    int p = (s + 1) & 1;
#pragma unroll
    for (int e = 0; e < 2; ++e) {
      int idx = tid + e * 256;
      int bi = idx >> 6, nn = idx & 63;
      float sum = ((red[0][bi][nn] + red[1][bi][nn]) + red[2][bi][nn]) + red[3][bi][nn];
      int b = b0 + bi, n = n0 + nn;
      float vold = out[b * VT_STRIDE_B + s * NDIM + n];
      float vnew = 0.9f * vold + 0.1f * sum;
      out[b * VT_STRIDE_B + (s + 1) * NDIM + n] = vnew;
      float sg = 1.0f / (1.0f + expf(-vnew));
      ws[S_OFF + p * (NB * NDIM) + b * NDIM + n] = sg;
      ws[TH_OFF + p * (NB * NDIM) + b * NDIM + n] = tanhf(vnew);
      float zarg = (0.1f * (vnew - 0.4f)) / 0.4f;
      float zs = 1.0f / (1.0f + expf(-zarg));
      float u = noise[(b * TT + s) * NDIM + n];
      out[ZT_BASE + b * VT_STRIDE_B + (s + 1) * NDIM + n] = (zs > u) ? 1.0f : 0.0f;
    }
  } else {
    if (s < 1) return;
    int bb = blk - 512;          // 0..127
    int b0 = (bb >> 1) * 4;      // 64 batch groups of 4
    int o0 = (bb & 1) * 64;      // 2 output halves
    const float* Tb = ws + TH_OFF + (s & 1) * (NB * NDIM);
    const float* Wt = ws + WT_OFF;
    float acc[4] = {0.f, 0.f, 0.f, 0.f};
    int kb = w * 256, ke = kb + 256;
#pragma unroll 4
    for (int k = kb; k < ke; ++k) {
      float wv = Wt[k * ODIM + o0 + l];
#pragma unroll
      for (int i = 0; i < 4; ++i)
        acc[i] = fmaf(Tb[(b0 + i) * NDIM + k], wv, acc[i]);
    }
#pragma unroll
    for (int i = 0; i < 4; ++i) red[w][i][l] = acc[i];
    __syncthreads();
    int bi = tid >> 6, oo = tid & 63;
    float sum = ((red[0][bi][oo] + red[1][bi][oo]) + red[2][bi][oo]) + red[3][bi][oo];
    out[OUTS_BASE + ((b0 + bi) * TT + (s - 1)) * ODIM + o0 + oo] = sum;
  }
}

extern "C" void kernel_launch(void* const* d_in, const int* in_sizes, int n_in,
                              void* d_out, int out_size, void* d_ws, size_t ws_size,
                              hipStream_t stream) {
  const float* inputs = (const float*)d_in[0];  // (256,200,128)
  const float* noise  = (const float*)d_in[1];  // (256,200,1024)
  const float* J      = (const float*)d_in[2];  // (1024,1024)
  const float* Bm     = (const float*)d_in[3];  // (1024,128)
  const float* W      = (const float*)d_in[4];  // (128,1024)
  float* out = (float*)d_out;
  float* ws  = (float*)d_ws;  // needs >= 9,437,184 bytes

  rsnn_prologue<<<1536, 256, 0, stream>>>(J, Bm, W, ws, out);
  for (int s = 0; s <= TT; ++s) {
    rsnn_step<<<640, 256, 0, stream>>>(inputs, noise, ws, out, s);
  }
}

// Round 5
// 7759.119 us; speedup vs baseline: 1.1436x; 1.1436x over previous
//
#include <hip/hip_runtime.h>
#include <math.h>

#define TT 200
#define NDIM 1024
#define IDIM 128
#define ODIM 128
#define NB 256

// ws float offsets (total 2,359,296 floats = 9,437,184 B; R1 proved this size)
#define JT_OFF 0          // f32 Jt[k][n] = J[n][k]           (1024x1024)
#define BT_OFF 1048576    // f32 Bt[i][n] = B[n][i]           (128x1024)
#define WT_OFF 1179648    // f32 Wt[k][o] = W[o][k]           (1024x128)
#define S_OFF  1310720    // f32 [2][256][1024] sigmoid(V)
#define TH_OFF 1835008    // f32 [2][256][1024] tanh(V)

// d_out float offsets
#define VT_STRIDE 205824          // 201*1024 per batch
#define ZT_BASE   52690944        // 256*201*1024
#define OUTS_BASE 105381888

__global__ __launch_bounds__(256) void rsnn_prologue(
    const float* __restrict__ J, const float* __restrict__ Bm,
    const float* __restrict__ W, float* __restrict__ ws,
    float* __restrict__ out) {
  int blk = blockIdx.x, tid = threadIdx.x;
  __shared__ float tile[32][33];
  if (blk < 1024) {
    // transpose J (1024x1024) -> Jt[k][n]
    int tk = blk >> 5, tn = blk & 31;
    int k0 = tk * 32, n0 = tn * 32;
    int c = tid & 31, r0 = tid >> 5;
#pragma unroll
    for (int j = 0; j < 4; ++j) {
      int r = r0 + j * 8;
      tile[r][c] = J[(n0 + r) * NDIM + (k0 + c)];
    }
    __syncthreads();
#pragma unroll
    for (int j = 0; j < 4; ++j) {
      int r = r0 + j * 8;
      ws[JT_OFF + (k0 + r) * NDIM + (n0 + c)] = tile[c][r];
    }
  } else if (blk < 1152) {
    // transpose B (1024x128) -> Bt[i][n]
    int b2 = blk - 1024;
    int tn = b2 >> 2, ti = b2 & 3;
    int n0 = tn * 32, i0 = ti * 32;
    int c = tid & 31, r0 = tid >> 5;
#pragma unroll
    for (int j = 0; j < 4; ++j) {
      int r = r0 + j * 8;
      tile[r][c] = Bm[(n0 + r) * IDIM + (i0 + c)];
    }
    __syncthreads();
#pragma unroll
    for (int j = 0; j < 4; ++j) {
      int r = r0 + j * 8;
      ws[BT_OFF + (i0 + r) * NDIM + (n0 + c)] = tile[c][r];
    }
  } else if (blk < 1280) {
    // transpose W (128x1024) -> Wt[k][o]
    int b3 = blk - 1152;
    int to = b3 >> 5, tn = b3 & 31;
    int o0 = to * 32, n0 = tn * 32;
    int c = tid & 31, r0 = tid >> 5;
#pragma unroll
    for (int j = 0; j < 4; ++j) {
      int r = r0 + j * 8;
      tile[r][c] = W[(o0 + r) * NDIM + (n0 + c)];
    }
    __syncthreads();
#pragma unroll
    for (int j = 0; j < 4; ++j) {
      int r = r0 + j * 8;
      ws[WT_OFF + (n0 + r) * ODIM + (o0 + c)] = tile[c][r];
    }
  } else {
    // init: S parity0 = sigmoid(0) = 0.5 ; vt[:,0,:] = 0 ; zt[:,0,:] = 0
    int i0 = (blk - 1280) * 256 + tid;
    for (int it = i0; it < NB * NDIM; it += 256 * 256) {
      int b = it >> 10, n = it & 1023;
      ws[S_OFF + it] = 0.5f;
      out[b * VT_STRIDE + n] = 0.0f;
      out[ZT_BASE + b * VT_STRIDE + n] = 0.0f;
    }
  }
}

// 256 blocks (bt=blk>>3: 8 batches, nt=blk&7: 128 neurons), 512 threads = 8 waves.
// Recurrent GEMM: wave w -> nsub=w>>2 (64-n half), kw=w&3 (R1's k-chunks
// {0-287,288-575,576-863,864-1023 + input-proj}) — per-(b,n) fmaf chains and the
// ((0+1)+2)+3 reduce are BIT-IDENTICAL to round 1's passing kernel.
// outs GEMM (step s-1): R1's 4x256-k chains, ((0+1)+2)+3, folded into same blocks.
__global__ __launch_bounds__(512, 1) void rsnn_step(
    const float* __restrict__ inputs, const float* __restrict__ noise,
    float* __restrict__ ws, float* __restrict__ out, int s) {
  const int tid = threadIdx.x;
  const int l = tid & 63;
  const int w = __builtin_amdgcn_readfirstlane(tid >> 6);
  const int bt = blockIdx.x >> 3, nt = blockIdx.x & 7;
  const int b0 = bt << 3;

  // S_lds[k][b] stride 12 floats (48 B: 16B-aligned for b128, banks spread)
  __shared__ float S_lds[NDIM * 12];
  __shared__ float X_lds[IDIM * 12];
  __shared__ float red[8][8][64];
  __shared__ float red2[4][8][16];

  if (s < TT) {
    const float* Sb = ws + S_OFF + (s & 1) * (NB * NDIM);
    const int r = tid >> 6;            // batch row 0..7
    const int c = (tid & 63) << 2;     // col base
    const float* srow = Sb + (b0 + r) * NDIM;
#pragma unroll
    for (int j = 0; j < 4; ++j) {
      const int cj = c + (j << 8);
      float4 v = *(const float4*)(srow + cj);
      S_lds[(cj + 0) * 12 + r] = v.x;
      S_lds[(cj + 1) * 12 + r] = v.y;
      S_lds[(cj + 2) * 12 + r] = v.z;
      S_lds[(cj + 3) * 12 + r] = v.w;
    }
    const int cx = (tid & 63) << 1;
    float2 xv = *(const float2*)(inputs + ((size_t)(b0 + r) * TT + s) * IDIM + cx);
    X_lds[cx * 12 + r] = xv.x;
    X_lds[(cx + 1) * 12 + r] = xv.y;
  }
  __syncthreads();

  if (s < TT) {
    const int nsub = w >> 2, kw = w & 3;
    const int n = (nt << 7) + (nsub << 6) + l;
    const float* JTp = ws + JT_OFF;
    float acc[8] = {0.f, 0.f, 0.f, 0.f, 0.f, 0.f, 0.f, 0.f};
    const int kb = kw * 288;
    const int ke = (kb + 288 < NDIM) ? (kb + 288) : NDIM;
#pragma unroll 4
    for (int k = kb; k < ke; ++k) {
      float jv = JTp[k * NDIM + n];                     // coalesced L2 stream
      float4 s0 = *(const float4*)&S_lds[k * 12];       // broadcast b128
      float4 s1 = *(const float4*)&S_lds[k * 12 + 4];
      acc[0] = fmaf(s0.x, jv, acc[0]);
      acc[1] = fmaf(s0.y, jv, acc[1]);
      acc[2] = fmaf(s0.z, jv, acc[2]);
      acc[3] = fmaf(s0.w, jv, acc[3]);
      acc[4] = fmaf(s1.x, jv, acc[4]);
      acc[5] = fmaf(s1.y, jv, acc[5]);
      acc[6] = fmaf(s1.z, jv, acc[6]);
      acc[7] = fmaf(s1.w, jv, acc[7]);
    }
    if (kw == 3) {  // input projection appended to wave-3's chain (as in R1)
      const float* BTp = ws + BT_OFF;
#pragma unroll 4
      for (int k2 = 0; k2 < IDIM; ++k2) {
        float bv = BTp[k2 * NDIM + n];
        float4 x0 = *(const float4*)&X_lds[k2 * 12];
        float4 x1 = *(const float4*)&X_lds[k2 * 12 + 4];
        acc[0] = fmaf(x0.x, bv, acc[0]);
        acc[1] = fmaf(x0.y, bv, acc[1]);
        acc[2] = fmaf(x0.z, bv, acc[2]);
        acc[3] = fmaf(x0.w, bv, acc[3]);
        acc[4] = fmaf(x1.x, bv, acc[4]);
        acc[5] = fmaf(x1.y, bv, acc[5]);
        acc[6] = fmaf(x1.z, bv, acc[6]);
        acc[7] = fmaf(x1.w, bv, acc[7]);
      }
    }
#pragma unroll
    for (int i = 0; i < 8; ++i) red[w][i][l] = acc[i];
  }

  if (s >= 1) {  // outs for step s-1: 8 waves cover 4 k-chunks x (8b x 16o)
    const float* Tb = ws + TH_OFF + (s & 1) * (NB * NDIM);
    const float* WTp = ws + WT_OFF;
    const int kw2 = w >> 1;
    const int idx2 = ((w & 1) << 6) + l;
    const int i = idx2 >> 4, oo = idx2 & 15;
    const int o = (nt << 4) + oo;
    const float* trow = Tb + (size_t)(b0 + i) * NDIM;
    float acco = 0.f;
    const int k0 = kw2 << 8;
#pragma unroll 4
    for (int k = k0; k < k0 + 256; ++k)
      acco = fmaf(trow[k], WTp[k * ODIM + o], acco);
    red2[kw2][i][oo] = acco;
  }

  __syncthreads();

  if (s < TT) {
    const int p = (s + 1) & 1;
#pragma unroll
    for (int e = 0; e < 2; ++e) {
      const int idx = (e << 9) + tid;        // 0..1023 over 8b x 128n
      const int i = idx >> 7, nc = idx & 127;
      const int ns2 = nc >> 6, ll = nc & 63;
      float sum = ((red[ns2 * 4 + 0][i][ll] + red[ns2 * 4 + 1][i][ll]) +
                   red[ns2 * 4 + 2][i][ll]) + red[ns2 * 4 + 3][i][ll];
      const int b = b0 + i;
      const int n = (nt << 7) + nc;
      float vold = out[b * VT_STRIDE + s * NDIM + n];
      float vnew = 0.9f * vold + 0.1f * sum;
      out[b * VT_STRIDE + (s + 1) * NDIM + n] = vnew;
      float sg = 1.0f / (1.0f + expf(-vnew));
      ws[S_OFF + p * (NB * NDIM) + b * NDIM + n] = sg;
      ws[TH_OFF + p * (NB * NDIM) + b * NDIM + n] = tanhf(vnew);
      float zarg = (0.1f * (vnew - 0.4f)) / 0.4f;
      float zs = 1.0f / (1.0f + expf(-zarg));
      float u = noise[(b * TT + s) * NDIM + n];
      out[ZT_BASE + b * VT_STRIDE + (s + 1) * NDIM + n] = (zs > u) ? 1.0f : 0.0f;
    }
  }

  if (s >= 1 && tid < 128) {
    const int i = tid >> 4, oo = tid & 15;
    float sum = ((red2[0][i][oo] + red2[1][i][oo]) + red2[2][i][oo]) + red2[3][i][oo];
    out[OUTS_BASE + ((size_t)(b0 + i) * TT + (s - 1)) * ODIM + (nt << 4) + oo] = sum;
  }
}

extern "C" void kernel_launch(void* const* d_in, const int* in_sizes, int n_in,
                              void* d_out, int out_size, void* d_ws, size_t ws_size,
                              hipStream_t stream) {
  const float* inputs = (const float*)d_in[0];  // (256,200,128)
  const float* noise  = (const float*)d_in[1];  // (256,200,1024)
  const float* J      = (const float*)d_in[2];  // (1024,1024)
  const float* Bm     = (const float*)d_in[3];  // (1024,128)
  const float* W      = (const float*)d_in[4];  // (128,1024)
  float* out = (float*)d_out;
  float* ws  = (float*)d_ws;

  rsnn_prologue<<<1536, 256, 0, stream>>>(J, Bm, W, ws, out);
  for (int s = 0; s <= TT; ++s) {
    rsnn_step<<<256, 512, 0, stream>>>(inputs, noise, ws, out, s);
  }
}